// Round 1
// 291.364 us; speedup vs baseline: 1.0275x; 1.0275x over previous
//
#include <hip/hip_runtime.h>
#include <math.h>

namespace {
constexpr int B = 32, H = 56, W = 56, C = 256;
constexpr int HW  = H * W;      // 3136
constexpr int WC  = W * C;      // 14336
constexpr int HC  = H * C;      // 14336
constexpr int HWC = H * W * C;  // 802816
constexpr int CH  = 32;         // SE hidden
constexpr float BN_EPS = 1e-3f;

using f4v = __attribute__((ext_vector_type(4))) float;

__device__ __forceinline__ float sigmoidf_(float v) { return 1.0f / (1.0f + expf(-v)); }

__device__ __forceinline__ void nt_store_float4(float* p, const float4& o) {
    union { float4 s; f4v v; } u;
    u.s = o;
    __builtin_nontemporal_store(u.v, (f4v*)p);
}
} // namespace

// ============ K1: all pools, uniform 56KB-per-block work ====================
// blocks [0, B*H): row family -> pool1 (over W) + pool3 (over C) for (b,h)
// blocks [B*H, B*H+B*W): col family -> pool2 (over H) for one (b,w) column
__global__ __launch_bounds__(256)
void pool_all_kernel(const float* __restrict__ x,
                     float* __restrict__ pmax1, float* __restrict__ pavg1,
                     float* __restrict__ pmax2, float* __restrict__ pavg2,
                     float* __restrict__ pmax3, float* __restrict__ pavg3) {
    const int t = threadIdx.x;
    const int lane = t & 63, sub = t >> 6;
    const int c4 = lane * 4;
    __shared__ float smx[4][256];
    __shared__ float ssm[4][256];

    if (blockIdx.x < B * H) {
        const int b = blockIdx.x / H, h = blockIdx.x % H;
        const float* xp = x + (size_t)b * HWC + (size_t)h * WC + c4;
        // hoist all loads: 14 independent float4 loads in flight
        float4 v[14];
        #pragma unroll
        for (int wq = 0; wq < 14; ++wq)
            v[wq] = *(const float4*)(xp + (wq * 4 + sub) * C);
        // pool1 (over W): per-thread partial over its 14 w's
        float4 mx = v[0], sm = v[0];
        #pragma unroll
        for (int wq = 1; wq < 14; ++wq) {
            mx.x = fmaxf(mx.x, v[wq].x); mx.y = fmaxf(mx.y, v[wq].y);
            mx.z = fmaxf(mx.z, v[wq].z); mx.w = fmaxf(mx.w, v[wq].w);
            sm.x += v[wq].x; sm.y += v[wq].y; sm.z += v[wq].z; sm.w += v[wq].w;
        }
        // pool3 (over C): 14 independent shuffle chains (ILP across wq)
        #pragma unroll
        for (int wq = 0; wq < 14; ++wq) {
            float m3 = fmaxf(fmaxf(v[wq].x, v[wq].y), fmaxf(v[wq].z, v[wq].w));
            float s3 = v[wq].x + v[wq].y + v[wq].z + v[wq].w;
            #pragma unroll
            for (int off = 32; off > 0; off >>= 1) {
                m3 = fmaxf(m3, __shfl_down(m3, off));
                s3 += __shfl_down(s3, off);
            }
            if (lane == 0) {
                const int w = wq * 4 + sub;
                pmax3[b * HW + h * W + w] = m3;
                pavg3[b * HW + h * W + w] = s3 * (1.0f / C);
            }
        }
        *(float4*)&smx[sub][c4] = mx;
        *(float4*)&ssm[sub][c4] = sm;
        __syncthreads();
        const float m = fmaxf(fmaxf(smx[0][t], smx[1][t]), fmaxf(smx[2][t], smx[3][t]));
        const float s = ssm[0][t] + ssm[1][t] + ssm[2][t] + ssm[3][t];
        pmax1[b * HC + h * C + t] = m;
        pavg1[b * HC + h * C + t] = s * (1.0f / W);
    } else {
        // col family: one (b,w) column per block -> same 56KB work as row blocks
        const int tt = blockIdx.x - B * H;
        const int b = tt / W, w = tt % W;
        const float* xp = x + (size_t)b * HWC + (size_t)w * C + c4;
        float4 v[14];
        #pragma unroll
        for (int i = 0; i < 14; ++i)
            v[i] = *(const float4*)(xp + (size_t)(i * 4 + sub) * WC);
        float4 mx = v[0], sm = v[0];
        #pragma unroll
        for (int i = 1; i < 14; ++i) {
            mx.x = fmaxf(mx.x, v[i].x); mx.y = fmaxf(mx.y, v[i].y);
            mx.z = fmaxf(mx.z, v[i].z); mx.w = fmaxf(mx.w, v[i].w);
            sm.x += v[i].x; sm.y += v[i].y; sm.z += v[i].z; sm.w += v[i].w;
        }
        *(float4*)&smx[sub][c4] = mx;
        *(float4*)&ssm[sub][c4] = sm;
        __syncthreads();
        const float m = fmaxf(fmaxf(smx[0][t], smx[1][t]), fmaxf(smx[2][t], smx[3][t]));
        const float s = ssm[0][t] + ssm[1][t] + ssm[2][t] + ssm[3][t];
        pmax2[(size_t)b * WC + w * C + t] = m;
        pavg2[(size_t)b * WC + w * C + t] = s * (1.0f / H);
    }
}

// ============ K2: all three 7x7 convs + BN + sigmoid, float2 LDS pairs ======
__global__ __launch_bounds__(256)
void conv_all_kernel(const float* __restrict__ pmax1, const float* __restrict__ pavg1,
                     const float* __restrict__ pmax2, const float* __restrict__ pavg2,
                     const float* __restrict__ pmax3, const float* __restrict__ pavg3,
                     const float* __restrict__ c1w, const float* __restrict__ c1b,
                     const float* __restrict__ g1,  const float* __restrict__ be1,
                     const float* __restrict__ m1,  const float* __restrict__ v1,
                     const float* __restrict__ c2w, const float* __restrict__ c2b,
                     const float* __restrict__ g2,  const float* __restrict__ be2,
                     const float* __restrict__ m2,  const float* __restrict__ v2,
                     const float* __restrict__ c3w, const float* __restrict__ c3b,
                     const float* __restrict__ g3,  const float* __restrict__ be3,
                     const float* __restrict__ m3,  const float* __restrict__ v3,
                     float* __restrict__ a1, float* __restrict__ a2t, float* __restrict__ a3) {
    const int t = threadIdx.x;
    __shared__ float wg[98];
    __shared__ float2 sp[7][264];   // (max,avg) interleaved -> ds_read_b64 taps

    if (blockIdx.x < B * H) {
        // conv1: spatial (H, C), out a1[b][h][c]
        if (t < 98) wg[t] = c1w[t];
        const int b = blockIdx.x / H, h = blockIdx.x % H;
        const float* bm = pmax1 + (size_t)b * HC;
        const float* ba = pavg1 + (size_t)b * HC;
        #pragma unroll
        for (int ky = 0; ky < 7; ++ky) {
            const int hy = h + ky - 3;
            const bool val = (hy >= 0 && hy < H);
            const int hyc = min(max(hy, 0), H - 1);
            const float lm = bm[hyc * C + t];
            const float la = ba[hyc * C + t];
            sp[ky][t + 3] = val ? make_float2(lm, la) : make_float2(0.f, 0.f);
            if (t < 3) { sp[ky][t] = make_float2(0.f, 0.f); sp[ky][261 - t] = make_float2(0.f, 0.f); }
        }
        __syncthreads();
        const float A  = rsqrtf(v1[0] + BN_EPS) * g1[0];
        const float Bc = (c1b[0] - m1[0]) * A + be1[0];
        float acc = 0.f;
        #pragma unroll
        for (int ky = 0; ky < 7; ++ky)
            #pragma unroll
            for (int kx = 0; kx < 7; ++kx) {
                const float2 p = sp[ky][t + kx];
                acc += p.x * wg[ky * 14 + kx * 2] + p.y * wg[ky * 14 + kx * 2 + 1];
            }
        a1[b * HC + h * C + t] = sigmoidf_(acc * A + Bc);
    } else if (blockIdx.x < 2 * B * H) {
        // conv2: spatial (C, W); pools [b][w][c]; out a2t[b][w][c]
        if (t < 98) wg[t] = c2w[t];
        const int tt = blockIdx.x - B * H;
        const int b = tt / W, w = tt % W;
        #pragma unroll
        for (int kx = 0; kx < 7; ++kx) {
            const int wx = w + kx - 3;
            const bool val = (wx >= 0 && wx < W);
            const int wxc = min(max(wx, 0), W - 1);
            const float lm = pmax2[(size_t)b * WC + wxc * C + t];
            const float la = pavg2[(size_t)b * WC + wxc * C + t];
            sp[kx][t + 3] = val ? make_float2(lm, la) : make_float2(0.f, 0.f);
            if (t < 3) { sp[kx][t] = make_float2(0.f, 0.f); sp[kx][261 - t] = make_float2(0.f, 0.f); }
        }
        __syncthreads();
        const float A  = rsqrtf(v2[0] + BN_EPS) * g2[0];
        const float Bc = (c2b[0] - m2[0]) * A + be2[0];
        float acc = 0.f;
        #pragma unroll
        for (int kx = 0; kx < 7; ++kx)
            #pragma unroll
            for (int ky = 0; ky < 7; ++ky) {
                const float2 p = sp[kx][t + ky];
                acc += p.x * wg[ky * 14 + kx * 2] + p.y * wg[ky * 14 + kx * 2 + 1];
            }
        a2t[(size_t)b * WC + w * C + t] = sigmoidf_(acc * A + Bc);
    } else {
        // conv3: spatial (H, W); block = (b, 4 h-rows), LDS-staged 10x62 halo tile
        if (t < 98) wg[t] = c3w[t];
        float2 (*sp3)[66] = (float2(*)[66])sp;   // 10 x 66 pairs = 5.3KB, fits in sp
        const int tt = blockIdx.x - 2 * B * H;
        const int b = tt / 14, h0 = (tt % 14) * 4;
        const float* bm = pmax3 + (size_t)b * HW;
        const float* ba = pavg3 + (size_t)b * HW;
        for (int idx = t; idx < 10 * 62; idx += 256) {
            const int r = idx / 62, col = idx % 62;
            const int hh = h0 + r - 3, ww = col - 3;
            const bool val = (hh >= 0 && hh < H && ww >= 0 && ww < W);
            const int hs = min(max(hh, 0), H - 1), wsx = min(max(ww, 0), W - 1);
            const float pm = bm[hs * W + wsx];
            const float pa = ba[hs * W + wsx];
            sp3[r][col] = val ? make_float2(pm, pa) : make_float2(0.f, 0.f);
        }
        __syncthreads();
        if (t < 224) {
            const int r = t / 56, w = t % 56;
            const float A  = rsqrtf(v3[0] + BN_EPS) * g3[0];
            const float Bc = (c3b[0] - m3[0]) * A + be3[0];
            float acc = 0.f;
            #pragma unroll
            for (int ky = 0; ky < 7; ++ky)
                #pragma unroll
                for (int kx = 0; kx < 7; ++kx) {
                    const float2 p = sp3[r + ky][w + kx];
                    acc += p.x * wg[ky * 14 + kx * 2] + p.y * wg[ky * 14 + kx * 2 + 1];
                }
            a3[b * HW + (h0 + r) * W + w] = sigmoidf_(acc * A + Bc);
        }
    }
}

// ============ K3: per-row a3-weighted partials: gpart[bh][c] = sum_w a3*x ====
__global__ __launch_bounds__(256)
void gap_row_kernel(const float* __restrict__ x, const float* __restrict__ a3,
                    float* __restrict__ gpart) {
    const int b = blockIdx.x / H, h = blockIdx.x % H;
    const int t = threadIdx.x;
    const int lane = t & 63, sub = t >> 6;
    const int c4 = lane * 4;
    const float* xp = x + (size_t)b * HWC + (size_t)h * WC + c4;
    const float* ap = a3 + b * HW + h * W + sub;
    float4 v[14]; float av[14];
    #pragma unroll
    for (int wq = 0; wq < 14; ++wq) {
        v[wq]  = *(const float4*)(xp + (wq * 4 + sub) * C);
        av[wq] = ap[wq * 4];
    }
    float4 acc = make_float4(0.f, 0.f, 0.f, 0.f);
    #pragma unroll
    for (int wq = 0; wq < 14; ++wq) {
        acc.x += v[wq].x * av[wq];
        acc.y += v[wq].y * av[wq];
        acc.z += v[wq].z * av[wq];
        acc.w += v[wq].w * av[wq];
    }
    __shared__ float sacc[4][256];
    *(float4*)&sacc[sub][c4] = acc;
    __syncthreads();
    gpart[(size_t)blockIdx.x * C + t] = sacc[0][t] + sacc[1][t] + sacc[2][t] + sacc[3][t];
}

// ============ K4: SE (parallel FC1: 8 partials/unit across 256 threads) =====
__global__ __launch_bounds__(256)
void se_kernel(const float* __restrict__ gpart,
               const float* __restrict__ a1,  const float* __restrict__ pavg1,
               const float* __restrict__ a2t, const float* __restrict__ pavg2,
               const float* __restrict__ w1, const float* __restrict__ b1,
               const float* __restrict__ w2, const float* __restrict__ b2,
               float* __restrict__ cw) {
    const int b = blockIdx.x;
    const int t = threadIdx.x;
    __shared__ float gs[C];
    __shared__ float part[8][33];
    __shared__ float hs[CH];
    const float* pa = a1    + (size_t)b * HC + t;
    const float* pv = pavg1 + (size_t)b * HC + t;
    const float* qa = a2t   + (size_t)b * WC + t;
    const float* qv = pavg2 + (size_t)b * WC + t;
    const float* gp = gpart + (size_t)b * H * C + t;
    float s1 = 0.f, s2 = 0.f, s3 = 0.f;
    #pragma unroll 8
    for (int r = 0; r < H; ++r) {
        s1 += pa[r * C] * pv[r * C];
        s2 += qa[r * C] * qv[r * C];
        s3 += gp[r * C];
    }
    // gap = (s1+s2)/56 + s3/3136
    gs[t] = (s1 + s2) * (1.0f / 56.0f) + s3 * (1.0f / (float)HW);
    __syncthreads();
    // FC1: hidden unit d = t&31, column block j = t>>5 (8 partials per unit)
    {
        const int d = t & 31, j = t >> 5;
        float a = 0.f;
        #pragma unroll
        for (int i = 0; i < 32; ++i) {
            const int c = j * 32 + i;
            a += gs[c] * w1[c * CH + d];
        }
        part[j][d] = a;
    }
    __syncthreads();
    if (t < CH) {
        float a = b1[t];
        #pragma unroll
        for (int j = 0; j < 8; ++j) a += part[j][t];
        hs[t] = fmaxf(a, 0.f);
    }
    __syncthreads();
    float a = b2[t];
    #pragma unroll
    for (int d = 0; d < CH; ++d) a += hs[d] * w2[d * C + t];
    cw[b * C + t] = sigmoidf_(a);
}

// ============ K5: out = x*(a1+a2+a3)*cw, one row per block ===================
__global__ __launch_bounds__(256)
void out_row_kernel(const float* __restrict__ x, const float* __restrict__ a1,
                    const float* __restrict__ a2t, const float* __restrict__ a3,
                    const float* __restrict__ cw, float* __restrict__ out) {
    const int b = blockIdx.x / H, h = blockIdx.x % H;
    const int t = threadIdx.x;
    const int lane = t & 63, sub = t >> 6;
    const int c4 = lane * 4;
    const float* xp  = x   + (size_t)b * HWC + (size_t)h * WC + c4;
    const float* a2b = a2t + (size_t)b * WC + c4;
    float*       op  = out + (size_t)b * HWC + (size_t)h * WC + c4;
    const float4 a1v = *(const float4*)(a1 + b * HC + h * C + c4);
    const float4 cwv = *(const float4*)(cw + b * C + c4);
    const float* ap = a3 + b * HW + h * W + sub;
    #pragma unroll
    for (int wq = 0; wq < 14; ++wq) {
        const int off = (wq * 4 + sub) * C;
        const float4 xv  = *(const float4*)(xp  + off);
        const float4 a2v = *(const float4*)(a2b + off);
        const float a3v  = ap[wq * 4];
        float4 o;
        o.x = xv.x * (a1v.x + a2v.x + a3v) * cwv.x;
        o.y = xv.y * (a1v.y + a2v.y + a3v) * cwv.y;
        o.z = xv.z * (a1v.z + a2v.z + a3v) * cwv.z;
        o.w = xv.w * (a1v.w + a2v.w + a3v) * cwv.w;
        nt_store_float4(op + off, o);
    }
}

extern "C" void kernel_launch(void* const* d_in, const int* in_sizes, int n_in,
                              void* d_out, int out_size, void* d_ws, size_t ws_size,
                              hipStream_t stream) {
    const float* x   = (const float*)d_in[0];
    const float* c1w = (const float*)d_in[1];  const float* c1b = (const float*)d_in[2];
    const float* g1  = (const float*)d_in[3];  const float* be1 = (const float*)d_in[4];
    const float* m1  = (const float*)d_in[5];  const float* v1  = (const float*)d_in[6];
    const float* c2w = (const float*)d_in[7];  const float* c2b = (const float*)d_in[8];
    const float* g2  = (const float*)d_in[9];  const float* be2 = (const float*)d_in[10];
    const float* m2  = (const float*)d_in[11]; const float* v2  = (const float*)d_in[12];
    const float* c3w = (const float*)d_in[13]; const float* c3b = (const float*)d_in[14];
    const float* g3  = (const float*)d_in[15]; const float* be3 = (const float*)d_in[16];
    const float* m3  = (const float*)d_in[17]; const float* v3  = (const float*)d_in[18];
    const float* sw1 = (const float*)d_in[19]; const float* sb1 = (const float*)d_in[20];
    const float* sw2 = (const float*)d_in[21]; const float* sb2 = (const float*)d_in[22];

    float* ws = (float*)d_ws;
    float* pmax1 = ws;                       // [B][H][C]
    float* pavg1 = pmax1 + (size_t)B * HC;
    float* pmax2 = pavg1 + (size_t)B * HC;   // [B][W][C]
    float* pavg2 = pmax2 + (size_t)B * WC;
    float* pmax3 = pavg2 + (size_t)B * WC;   // [B][H][W]
    float* pavg3 = pmax3 + (size_t)B * HW;
    float* a1    = pavg3 + (size_t)B * HW;   // [B][H][C]
    float* a2t   = a1    + (size_t)B * HC;   // [B][W][C]
    float* a3    = a2t   + (size_t)B * WC;   // [B][H][W]
    float* gpart = a3    + (size_t)B * HW;   // [B*H][C]
    float* cwv   = gpart + (size_t)B * H * C;// [B][C]

    pool_all_kernel<<<B * H + B * W, 256, 0, stream>>>(x, pmax1, pavg1, pmax2, pavg2, pmax3, pavg3);
    conv_all_kernel<<<2 * B * H + B * 14, 256, 0, stream>>>(
        pmax1, pavg1, pmax2, pavg2, pmax3, pavg3,
        c1w, c1b, g1, be1, m1, v1,
        c2w, c2b, g2, be2, m2, v2,
        c3w, c3b, g3, be3, m3, v3,
        a1, a2t, a3);
    gap_row_kernel<<<B * H, 256, 0, stream>>>(x, a3, gpart);
    se_kernel<<<B, 256, 0, stream>>>(gpart, a1, pavg1, a2t, pavg2, sw1, sb1, sw2, sb2, cwv);
    out_row_kernel<<<B * H, 256, 0, stream>>>(x, a1, a2t, a3, cwv, (float*)d_out);
}

// Round 3
// 287.368 us; speedup vs baseline: 1.0418x; 1.0139x over previous
//
#include <hip/hip_runtime.h>
#include <math.h>

namespace {
constexpr int B = 32, H = 56, W = 56, C = 256;
constexpr int HW  = H * W;      // 3136
constexpr int WC  = W * C;      // 14336
constexpr int HC  = H * C;      // 14336
constexpr int HWC = H * W * C;  // 802816
constexpr int CH  = 32;         // SE hidden
constexpr float BN_EPS = 1e-3f;

__device__ __forceinline__ float sigmoidf_(float v) { return 1.0f / (1.0f + expf(-v)); }
} // namespace

// ============ K1: all pools, uniform 56KB-per-block work ====================
// blocks [0, B*H): row family -> pool1 (over W) + pool3 (over C) for (b,h)
// blocks [B*H, B*H+B*W): col family -> pool2 (over H) for one (b,w) column
__global__ __launch_bounds__(256)
void pool_all_kernel(const float* __restrict__ x,
                     float* __restrict__ pmax1, float* __restrict__ pavg1,
                     float* __restrict__ pmax2, float* __restrict__ pavg2,
                     float* __restrict__ pmax3, float* __restrict__ pavg3) {
    const int t = threadIdx.x;
    const int lane = t & 63, sub = t >> 6;
    const int c4 = lane * 4;
    __shared__ float smx[4][256];
    __shared__ float ssm[4][256];

    if (blockIdx.x < B * H) {
        const int b = blockIdx.x / H, h = blockIdx.x % H;
        const float* xp = x + (size_t)b * HWC + (size_t)h * WC + c4;
        float4 v[14];
        #pragma unroll
        for (int wq = 0; wq < 14; ++wq)
            v[wq] = *(const float4*)(xp + (wq * 4 + sub) * C);
        // pool1 (over W): per-thread partial over its 14 w's
        float4 mx = v[0], sm = v[0];
        #pragma unroll
        for (int wq = 1; wq < 14; ++wq) {
            mx.x = fmaxf(mx.x, v[wq].x); mx.y = fmaxf(mx.y, v[wq].y);
            mx.z = fmaxf(mx.z, v[wq].z); mx.w = fmaxf(mx.w, v[wq].w);
            sm.x += v[wq].x; sm.y += v[wq].y; sm.z += v[wq].z; sm.w += v[wq].w;
        }
        // pool3 (over C): 14 independent shuffle chains
        #pragma unroll
        for (int wq = 0; wq < 14; ++wq) {
            float m3 = fmaxf(fmaxf(v[wq].x, v[wq].y), fmaxf(v[wq].z, v[wq].w));
            float s3 = v[wq].x + v[wq].y + v[wq].z + v[wq].w;
            #pragma unroll
            for (int off = 32; off > 0; off >>= 1) {
                m3 = fmaxf(m3, __shfl_down(m3, off));
                s3 += __shfl_down(s3, off);
            }
            if (lane == 0) {
                const int w = wq * 4 + sub;
                pmax3[b * HW + h * W + w] = m3;
                pavg3[b * HW + h * W + w] = s3 * (1.0f / C);
            }
        }
        *(float4*)&smx[sub][c4] = mx;
        *(float4*)&ssm[sub][c4] = sm;
        __syncthreads();
        const float m = fmaxf(fmaxf(smx[0][t], smx[1][t]), fmaxf(smx[2][t], smx[3][t]));
        const float s = ssm[0][t] + ssm[1][t] + ssm[2][t] + ssm[3][t];
        pmax1[b * HC + h * C + t] = m;
        pavg1[b * HC + h * C + t] = s * (1.0f / W);
    } else {
        const int tt = blockIdx.x - B * H;
        const int b = tt / W, w = tt % W;
        const float* xp = x + (size_t)b * HWC + (size_t)w * C + c4;
        float4 v[14];
        #pragma unroll
        for (int i = 0; i < 14; ++i)
            v[i] = *(const float4*)(xp + (size_t)(i * 4 + sub) * WC);
        float4 mx = v[0], sm = v[0];
        #pragma unroll
        for (int i = 1; i < 14; ++i) {
            mx.x = fmaxf(mx.x, v[i].x); mx.y = fmaxf(mx.y, v[i].y);
            mx.z = fmaxf(mx.z, v[i].z); mx.w = fmaxf(mx.w, v[i].w);
            sm.x += v[i].x; sm.y += v[i].y; sm.z += v[i].z; sm.w += v[i].w;
        }
        *(float4*)&smx[sub][c4] = mx;
        *(float4*)&ssm[sub][c4] = sm;
        __syncthreads();
        const float m = fmaxf(fmaxf(smx[0][t], smx[1][t]), fmaxf(smx[2][t], smx[3][t]));
        const float s = ssm[0][t] + ssm[1][t] + ssm[2][t] + ssm[3][t];
        pmax2[(size_t)b * WC + w * C + t] = m;
        pavg2[(size_t)b * WC + w * C + t] = s * (1.0f / H);
    }
}

// ============ K2: three 7x7 convs + BN + sigmoid; conv3 blocks also compute
//              gpart[b*H+h][c] = sum_w a3[b,h,w] * x[b,h,w,c]  (gap fused) ===
// grid: [0,448) conv3+gap (heavy, first) | [448,2240) conv1 | [2240,4032) conv2
__global__ __launch_bounds__(256)
void conv_all_kernel(const float* __restrict__ x,
                     const float* __restrict__ pmax1, const float* __restrict__ pavg1,
                     const float* __restrict__ pmax2, const float* __restrict__ pavg2,
                     const float* __restrict__ pmax3, const float* __restrict__ pavg3,
                     const float* __restrict__ c1w, const float* __restrict__ c1b,
                     const float* __restrict__ g1,  const float* __restrict__ be1,
                     const float* __restrict__ m1,  const float* __restrict__ v1,
                     const float* __restrict__ c2w, const float* __restrict__ c2b,
                     const float* __restrict__ g2,  const float* __restrict__ be2,
                     const float* __restrict__ m2,  const float* __restrict__ v2,
                     const float* __restrict__ c3w, const float* __restrict__ c3b,
                     const float* __restrict__ g3,  const float* __restrict__ be3,
                     const float* __restrict__ m3,  const float* __restrict__ v3,
                     float* __restrict__ a1, float* __restrict__ a2t, float* __restrict__ a3,
                     float* __restrict__ gpart) {
    const int t = threadIdx.x;
    __shared__ float wg[98];
    __shared__ float2 sp[7][264];   // (max,avg) pairs; conv3 overlays 10x66 here
    __shared__ float sa3[4][56];

    if (blockIdx.x < B * 14) {
        // ---- conv3 on (H,W) for 4 h-rows + fused gap partials ----
        if (t < 98) wg[t] = c3w[t];
        float2 (*sp3)[66] = (float2(*)[66])sp;
        const int tt = blockIdx.x;
        const int b = tt / 14, h0 = (tt % 14) * 4;
        const float* bm = pmax3 + (size_t)b * HW;
        const float* ba = pavg3 + (size_t)b * HW;
        for (int idx = t; idx < 10 * 62; idx += 256) {
            const int r = idx / 62, col = idx % 62;
            const int hh = h0 + r - 3, ww = col - 3;
            const bool val = (hh >= 0 && hh < H && ww >= 0 && ww < W);
            const int hs = min(max(hh, 0), H - 1), wsx = min(max(ww, 0), W - 1);
            const float pm = bm[hs * W + wsx];
            const float pa = ba[hs * W + wsx];
            sp3[r][col] = val ? make_float2(pm, pa) : make_float2(0.f, 0.f);
        }
        __syncthreads();
        if (t < 224) {
            const int r = t / 56, w = t % 56;
            const float A  = rsqrtf(v3[0] + BN_EPS) * g3[0];
            const float Bc = (c3b[0] - m3[0]) * A + be3[0];
            float acc = 0.f;
            #pragma unroll
            for (int ky = 0; ky < 7; ++ky)
                #pragma unroll
                for (int kx = 0; kx < 7; ++kx) {
                    const float2 p = sp3[r + ky][w + kx];
                    acc += p.x * wg[ky * 14 + kx * 2] + p.y * wg[ky * 14 + kx * 2 + 1];
                }
            const float av = sigmoidf_(acc * A + Bc);
            a3[b * HW + (h0 + r) * W + w] = av;
            sa3[r][w] = av;
        }
        __syncthreads();
        // gap partials: sub-wave owns row h0+sub, lanes own channels
        const int lane = t & 63, sub = t >> 6;
        const int c4 = lane * 4;
        const float* xp = x + (size_t)b * HWC + (size_t)(h0 + sub) * WC + c4;
        float4 acc4 = make_float4(0.f, 0.f, 0.f, 0.f);
        #pragma unroll 8
        for (int w = 0; w < W; ++w) {
            const float4 xv = *(const float4*)(xp + w * C);
            const float a3v = sa3[sub][w];
            acc4.x += xv.x * a3v;
            acc4.y += xv.y * a3v;
            acc4.z += xv.z * a3v;
            acc4.w += xv.w * a3v;
        }
        *(float4*)(gpart + (size_t)(b * H + h0 + sub) * C + c4) = acc4;
    } else if (blockIdx.x < B * 14 + B * H) {
        // ---- conv1: spatial (H, C), out a1[b][h][c] ----
        if (t < 98) wg[t] = c1w[t];
        const int tt = blockIdx.x - B * 14;
        const int b = tt / H, h = tt % H;
        const float* bm = pmax1 + (size_t)b * HC;
        const float* ba = pavg1 + (size_t)b * HC;
        #pragma unroll
        for (int ky = 0; ky < 7; ++ky) {
            const int hy = h + ky - 3;
            const bool val = (hy >= 0 && hy < H);
            const int hyc = min(max(hy, 0), H - 1);
            const float lm = bm[hyc * C + t];
            const float la = ba[hyc * C + t];
            sp[ky][t + 3] = val ? make_float2(lm, la) : make_float2(0.f, 0.f);
            if (t < 3) { sp[ky][t] = make_float2(0.f, 0.f); sp[ky][261 - t] = make_float2(0.f, 0.f); }
        }
        __syncthreads();
        const float A  = rsqrtf(v1[0] + BN_EPS) * g1[0];
        const float Bc = (c1b[0] - m1[0]) * A + be1[0];
        float acc = 0.f;
        #pragma unroll
        for (int ky = 0; ky < 7; ++ky)
            #pragma unroll
            for (int kx = 0; kx < 7; ++kx) {
                const float2 p = sp[ky][t + kx];
                acc += p.x * wg[ky * 14 + kx * 2] + p.y * wg[ky * 14 + kx * 2 + 1];
            }
        a1[b * HC + h * C + t] = sigmoidf_(acc * A + Bc);
    } else {
        // ---- conv2: spatial (C, W); pools [b][w][c]; out a2t[b][w][c] ----
        if (t < 98) wg[t] = c2w[t];
        const int tt = blockIdx.x - (B * 14 + B * H);
        const int b = tt / W, w = tt % W;
        #pragma unroll
        for (int kx = 0; kx < 7; ++kx) {
            const int wx = w + kx - 3;
            const bool val = (wx >= 0 && wx < W);
            const int wxc = min(max(wx, 0), W - 1);
            const float lm = pmax2[(size_t)b * WC + wxc * C + t];
            const float la = pavg2[(size_t)b * WC + wxc * C + t];
            sp[kx][t + 3] = val ? make_float2(lm, la) : make_float2(0.f, 0.f);
            if (t < 3) { sp[kx][t] = make_float2(0.f, 0.f); sp[kx][261 - t] = make_float2(0.f, 0.f); }
        }
        __syncthreads();
        const float A  = rsqrtf(v2[0] + BN_EPS) * g2[0];
        const float Bc = (c2b[0] - m2[0]) * A + be2[0];
        float acc = 0.f;
        #pragma unroll
        for (int kx = 0; kx < 7; ++kx)
            #pragma unroll
            for (int ky = 0; ky < 7; ++ky) {
                const float2 p = sp[kx][t + ky];
                acc += p.x * wg[ky * 14 + kx * 2] + p.y * wg[ky * 14 + kx * 2 + 1];
            }
        a2t[(size_t)b * WC + w * C + t] = sigmoidf_(acc * A + Bc);
    }
}

// ============ K3: SE (parallel FC1: 8 partials/unit across 256 threads) =====
__global__ __launch_bounds__(256)
void se_kernel(const float* __restrict__ gpart,
               const float* __restrict__ a1,  const float* __restrict__ pavg1,
               const float* __restrict__ a2t, const float* __restrict__ pavg2,
               const float* __restrict__ w1, const float* __restrict__ b1,
               const float* __restrict__ w2, const float* __restrict__ b2,
               float* __restrict__ cw) {
    const int b = blockIdx.x;
    const int t = threadIdx.x;
    __shared__ float gs[C];
    __shared__ float part[8][33];
    __shared__ float hs[CH];
    const float* pa = a1    + (size_t)b * HC + t;
    const float* pv = pavg1 + (size_t)b * HC + t;
    const float* qa = a2t   + (size_t)b * WC + t;
    const float* qv = pavg2 + (size_t)b * WC + t;
    const float* gp = gpart + (size_t)b * H * C + t;
    float s1 = 0.f, s2 = 0.f, s3 = 0.f;
    #pragma unroll 8
    for (int r = 0; r < H; ++r) {
        s1 += pa[r * C] * pv[r * C];
        s2 += qa[r * C] * qv[r * C];
        s3 += gp[r * C];
    }
    gs[t] = (s1 + s2) * (1.0f / 56.0f) + s3 * (1.0f / (float)HW);
    __syncthreads();
    {
        const int d = t & 31, j = t >> 5;
        float a = 0.f;
        #pragma unroll
        for (int i = 0; i < 32; ++i) {
            const int c = j * 32 + i;
            a += gs[c] * w1[c * CH + d];
        }
        part[j][d] = a;
    }
    __syncthreads();
    if (t < CH) {
        float a = b1[t];
        #pragma unroll
        for (int j = 0; j < 8; ++j) a += part[j][t];
        hs[t] = fmaxf(a, 0.f);
    }
    __syncthreads();
    float a = b2[t];
    #pragma unroll
    for (int d = 0; d < CH; ++d) a += hs[d] * w2[d * C + t];
    cw[b * C + t] = sigmoidf_(a);
}

// ============ K4: out = x*(a1+a2+a3)*cw, one row per block ===================
__global__ __launch_bounds__(256)
void out_row_kernel(const float* __restrict__ x, const float* __restrict__ a1,
                    const float* __restrict__ a2t, const float* __restrict__ a3,
                    const float* __restrict__ cw, float* __restrict__ out) {
    const int b = blockIdx.x / H, h = blockIdx.x % H;
    const int t = threadIdx.x;
    const int lane = t & 63, sub = t >> 6;
    const int c4 = lane * 4;
    const float* xp  = x   + (size_t)b * HWC + (size_t)h * WC + c4;
    const float* a2b = a2t + (size_t)b * WC + c4;
    float*       op  = out + (size_t)b * HWC + (size_t)h * WC + c4;
    const float4 a1v = *(const float4*)(a1 + b * HC + h * C + c4);
    const float4 cwv = *(const float4*)(cw + b * C + c4);
    const float* ap = a3 + b * HW + h * W + sub;
    #pragma unroll
    for (int wq = 0; wq < 14; ++wq) {
        const int off = (wq * 4 + sub) * C;
        const float4 xv  = *(const float4*)(xp  + off);
        const float4 a2v = *(const float4*)(a2b + off);
        const float a3v  = ap[wq * 4];
        float4 o;
        o.x = xv.x * (a1v.x + a2v.x + a3v) * cwv.x;
        o.y = xv.y * (a1v.y + a2v.y + a3v) * cwv.y;
        o.z = xv.z * (a1v.z + a2v.z + a3v) * cwv.z;
        o.w = xv.w * (a1v.w + a2v.w + a3v) * cwv.w;
        *(float4*)(op + off) = o;
    }
}

extern "C" void kernel_launch(void* const* d_in, const int* in_sizes, int n_in,
                              void* d_out, int out_size, void* d_ws, size_t ws_size,
                              hipStream_t stream) {
    const float* x   = (const float*)d_in[0];
    const float* c1w = (const float*)d_in[1];  const float* c1b = (const float*)d_in[2];
    const float* g1  = (const float*)d_in[3];  const float* be1 = (const float*)d_in[4];
    const float* m1  = (const float*)d_in[5];  const float* v1  = (const float*)d_in[6];
    const float* c2w = (const float*)d_in[7];  const float* c2b = (const float*)d_in[8];
    const float* g2  = (const float*)d_in[9];  const float* be2 = (const float*)d_in[10];
    const float* m2  = (const float*)d_in[11]; const float* v2  = (const float*)d_in[12];
    const float* c3w = (const float*)d_in[13]; const float* c3b = (const float*)d_in[14];
    const float* g3  = (const float*)d_in[15]; const float* be3 = (const float*)d_in[16];
    const float* m3  = (const float*)d_in[17]; const float* v3  = (const float*)d_in[18];
    const float* sw1 = (const float*)d_in[19]; const float* sb1 = (const float*)d_in[20];
    const float* sw2 = (const float*)d_in[21]; const float* sb2 = (const float*)d_in[22];

    float* ws = (float*)d_ws;
    float* pmax1 = ws;                       // [B][H][C]
    float* pavg1 = pmax1 + (size_t)B * HC;
    float* pmax2 = pavg1 + (size_t)B * HC;   // [B][W][C]
    float* pavg2 = pmax2 + (size_t)B * WC;
    float* pmax3 = pavg2 + (size_t)B * WC;   // [B][H][W]
    float* pavg3 = pmax3 + (size_t)B * HW;
    float* a1    = pavg3 + (size_t)B * HW;   // [B][H][C]
    float* a2t   = a1    + (size_t)B * HC;   // [B][W][C]
    float* a3    = a2t   + (size_t)B * WC;   // [B][H][W]
    float* gpart = a3    + (size_t)B * HW;   // [B*H][C]
    float* cwv   = gpart + (size_t)B * H * C;// [B][C]

    pool_all_kernel<<<B * H + B * W, 256, 0, stream>>>(x, pmax1, pavg1, pmax2, pavg2, pmax3, pavg3);
    conv_all_kernel<<<B * 14 + B * H + B * W, 256, 0, stream>>>(
        x, pmax1, pavg1, pmax2, pavg2, pmax3, pavg3,
        c1w, c1b, g1, be1, m1, v1,
        c2w, c2b, g2, be2, m2, v2,
        c3w, c3b, g3, be3, m3, v3,
        a1, a2t, a3, gpart);
    se_kernel<<<B, 256, 0, stream>>>(gpart, a1, pavg1, a2t, pavg2, sw1, sb1, sw2, sb2, cwv);
    out_row_kernel<<<B * H, 256, 0, stream>>>(x, a1, a2t, a3, cwv, (float*)d_out);
}